// Round 16
// baseline (70.227 us; speedup 1.0000x reference)
//
#include <hip/hip_runtime.h>
#include <math.h>

// LRPCHead: C=512, H=W=160 (HW=25600), NC=1203, LC=64
// Outputs (flat, fp32): loc_out [64*25600] | cls_out [1203*25600] | mask [25600]

constexpr int C_    = 512;
constexpr int HW_   = 25600;
constexpr int NC_   = 1203;
constexpr int VPAD_ = 1216;   // padded v-extent for AT/clsTmp (19*64)

constexpr int LOC_OFF_  = 0;
constexpr int CLS_OFF_  = 64 * HW_;              // 1,638,400
constexpr int MASK_OFF_ = CLS_OFF_ + NC_ * HW_;  // 32,435,200

constexpr int PF_BLOCKS_    = HW_ / 64;  // 400
constexpr int TRANS_BLOCKS_ = 19 * 8;    // 152
constexpr int LOC_BLOCKS_   = 400;
constexpr int FILL_BLOCKS_  = 2048;

typedef float vfloat4 __attribute__((ext_vector_type(4)));

// ---------------------------------------------------------------- init
__global__ void k_init(int* cnt) { *cnt = 0; }

// ---------------- dispatch 1: pf mask+compact+jLut | vocab transpose
__global__ __launch_bounds__(256) void k_pre(
    const float* __restrict__ cls_feat, const float* __restrict__ conf,
    const float* __restrict__ pf_w, const float* __restrict__ pf_b,
    const float* __restrict__ vocab_w, float* __restrict__ out,
    int* __restrict__ cnt, int* __restrict__ idxList,
    int* __restrict__ jLut, float* __restrict__ AT4, int jcap)
{
    const int bid = blockIdx.x;
    const int tid = threadIdx.x;

    if (bid < PF_BLOCKS_) {
        // ---- pf score + mask + compact (proven body) + jLut write
        __shared__ double sPart[256];
        const int hwi   = tid & 63;
        const int slice = tid >> 6;
        const int hw    = bid * 64 + hwi;
        const float* p  = cls_feat + (size_t)slice * 128 * HW_ + hw;
        const float* w  = pf_w + slice * 128;
        double acc = 0.0;
        #pragma unroll 4
        for (int k = 0; k < 128; ++k)
            acc += (double)w[k] * (double)p[(size_t)k * HW_];
        sPart[tid] = acc;
        __syncthreads();
        if (slice == 0) {
            double s = sPart[hwi] + sPart[64 + hwi] + sPart[128 + hwi] +
                       sPart[192 + hwi] + (double)pf_b[0];
            double sig = 1.0 / (1.0 + exp(-s));
            bool m = sig > (double)conf[0];
            out[MASK_OFF_ + hw] = m ? 1.0f : 0.0f;
            int pos = -1;
            if (m) {
                pos = atomicAdd(cnt, 1);
                if (pos < HW_) idxList[pos] = hw;
            }
            jLut[hw] = (m && pos >= 0 && pos < jcap) ? pos : -1;
        }
    } else {
        // ---- transpose vocab_w -> AT4[(k/4)][v][4] (proven body)
        if (jcap <= 0) return;
        const int tb = bid - PF_BLOCKS_;
        const int v0 = (tb % 19) * 64;
        const int k0 = (tb / 19) * 64;
        __shared__ float t[64][65];
        const int c  = tid & 63;
        const int r4 = tid >> 6;
        #pragma unroll
        for (int i = 0; i < 16; ++i) {
            const int r = r4 * 16 + i;
            const int v = v0 + r;
            t[r][c] = (v < NC_) ? vocab_w[(size_t)v * C_ + k0 + c] : 0.f;
        }
        __syncthreads();
        #pragma unroll
        for (int i = 0; i < 16; ++i) {
            const int k  = r4 * 16 + i;
            const int kg = k0 + k;
            AT4[((size_t)(kg >> 2) * VPAD_ + v0 + c) * 4 + (kg & 3)] = t[c][k];
        }
    }
}

// ------------- dispatch 2: gather live columns j-major BdT[j][k] (proven)
__global__ __launch_bounds__(256) void k_gatherJ(
    const float* __restrict__ cls_feat, const int* __restrict__ cnt,
    const int* __restrict__ idxList, float* __restrict__ BdT, int jcap)
{
    const int count = min(*cnt, HW_);
    if (count > jcap) return;  // fallback path will handle
    const int t = threadIdx.x;
    for (int j = blockIdx.x; j < count; j += gridDim.x) {
        const int hw = idxList[j];
        BdT[(size_t)j * C_ + t]       = cls_feat[(size_t)t * HW_ + hw];
        BdT[(size_t)j * C_ + 256 + t] = cls_feat[(size_t)(256 + t) * HW_ + hw];
    }
}

// ------------- dispatch 3: dense GEMM (round-12 gemm6 body -> clsTmp)
// block = 64 v x 4 j, K split across 4 waves, LDS reduce. grid (19, jcap/4).
// Runs BEFORE the big fill -> quiet memory system.
__global__ __launch_bounds__(256) void k_gemm6t(
    const float* __restrict__ AT4, const float* __restrict__ vocab_b,
    const int* __restrict__ cnt, const float* __restrict__ BdT,
    float* __restrict__ clsTmp, int jcap)
{
    const int count = min(*cnt, HW_);
    if (count == 0 || count > jcap) return;
    const int jBase = blockIdx.y * 4;
    if (jBase >= count) return;

    const int tid  = threadIdx.x;
    const int lane = tid & 63;
    const int w    = __builtin_amdgcn_readfirstlane(tid >> 6);  // wave 0..3
    const int v0   = blockIdx.x * 64;
    const int v    = v0 + lane;
    const float* __restrict__ Acol = AT4 + (size_t)v * 4;

    const int j0 = jBase + 0, j1 = jBase + 1, j2 = jBase + 2, j3 = jBase + 3;
    const float* __restrict__ B0 = BdT + (size_t)(j0 < count ? j0 : 0) * C_;
    const float* __restrict__ B1 = BdT + (size_t)(j1 < count ? j1 : 0) * C_;
    const float* __restrict__ B2 = BdT + (size_t)(j2 < count ? j2 : 0) * C_;
    const float* __restrict__ B3 = BdT + (size_t)(j3 < count ? j3 : 0) * C_;

    vfloat4 ac0 = {0,0,0,0}, ac1 = {0,0,0,0}, ac2 = {0,0,0,0}, ac3 = {0,0,0,0};
    const int kqBeg = w * 32;          // this wave's 128-k slice
    #pragma unroll 8
    for (int q = 0; q < 32; ++q) {
        const int kq = kqBeg + q;
        const vfloat4 a  = *(const vfloat4*)(Acol + (size_t)kq * VPAD_ * 4);
        const vfloat4 b0 = *(const vfloat4*)(B0 + kq * 4);
        const vfloat4 b1 = *(const vfloat4*)(B1 + kq * 4);
        const vfloat4 b2 = *(const vfloat4*)(B2 + kq * 4);
        const vfloat4 b3 = *(const vfloat4*)(B3 + kq * 4);
        ac0 += a * b0; ac1 += a * b1; ac2 += a * b2; ac3 += a * b3;
    }

    __shared__ float sRed[4][4][64];
    sRed[w][0][lane] = (ac0.x + ac0.y) + (ac0.z + ac0.w);
    sRed[w][1][lane] = (ac1.x + ac1.y) + (ac1.z + ac1.w);
    sRed[w][2][lane] = (ac2.x + ac2.y) + (ac2.z + ac2.w);
    sRed[w][3][lane] = (ac3.x + ac3.y) + (ac3.z + ac3.w);
    __syncthreads();

    if (tid < 64) {
        const float bias = (v < NC_) ? vocab_b[v] : 0.f;
        #pragma unroll
        for (int jj = 0; jj < 4; ++jj) {
            const int j = jBase + jj;
            if (j < count) {
                const float s =
                    (sRed[0][jj][lane] + sRed[1][jj][lane]) +
                    (sRed[2][jj][lane] + sRed[3][jj][lane]);
                clsTmp[(size_t)j * VPAD_ + v] = s + bias;
            }
        }
    }
}

// ---------------- dispatch 4: mega — loc conv | cls fill with live-splice
__global__ __launch_bounds__(256) void k_mega(
    const float* __restrict__ loc_feat, const float* __restrict__ vocab_b,
    const float* __restrict__ loc_w, const float* __restrict__ loc_b,
    const int* __restrict__ cnt, const int* __restrict__ jLut,
    const float* __restrict__ clsTmp, float* __restrict__ out, int jcap)
{
    const int bid = blockIdx.x;
    const int tid = threadIdx.x;

    if (bid < LOC_BLOCKS_) {
        // ----- loc 1x1 conv (proven body)
        const int j   = bid;
        const int hwb = j % 100;
        const int o0  = (j / 100) * 16;
        __shared__ float sw[16][64];
        for (int i = tid; i < 16 * 64; i += 256)
            sw[i >> 6][i & 63] = loc_w[(o0 + (i >> 6)) * 64 + (i & 63)];
        __syncthreads();
        const int hw = hwb * 256 + tid;
        float acc[16];
        #pragma unroll
        for (int r = 0; r < 16; ++r) acc[r] = loc_b[o0 + r];
        for (int i = 0; i < 64; ++i) {
            float f = loc_feat[(size_t)i * HW_ + hw];
            #pragma unroll
            for (int r = 0; r < 16; ++r) acc[r] += sw[r][i] * f;
        }
        #pragma unroll
        for (int r = 0; r < 16; ++r)
            out[LOC_OFF_ + (size_t)(o0 + r) * HW_ + hw] = acc[r];
    } else {
        // ----- fill cls_out with vocab_b, splicing live columns from clsTmp
        const int fb     = bid - LOC_BLOCKS_;
        const int count  = min(*cnt, HW_);
        const bool live  = (jcap > 0) && (count > 0) && (count <= jcap);
        const int hw4    = HW_ / 4;           // 6400
        const int total4 = NC_ * HW_ / 4;     // 7,699,200
        const int4* jLut4 = (const int4*)jLut;
        vfloat4* o = (vfloat4*)(out + CLS_OFF_);
        for (int i = fb * 256 + tid; i < total4; i += FILL_BLOCKS_ * 256) {
            const int v   = i / hw4;
            const int rem = i - v * hw4;
            const float b = vocab_b[v];
            vfloat4 val = {b, b, b, b};
            if (live) {
                const int4 jl = jLut4[rem];
                if ((jl.x | jl.y | jl.z | jl.w) >= 0 ||
                    jl.x >= 0 || jl.y >= 0 || jl.z >= 0 || jl.w >= 0) {
                    if (jl.x >= 0) val.x = clsTmp[(size_t)jl.x * VPAD_ + v];
                    if (jl.y >= 0) val.y = clsTmp[(size_t)jl.y * VPAD_ + v];
                    if (jl.z >= 0) val.z = clsTmp[(size_t)jl.z * VPAD_ + v];
                    if (jl.w >= 0) val.w = clsTmp[(size_t)jl.w * VPAD_ + v];
                }
            }
            __builtin_nontemporal_store(val, &o[i]);
        }
    }
}

// --------------------------- fallback: direct scatter-gather GEMM (count>jcap)
__global__ __launch_bounds__(256) void k_gemm_fallback(
    const float* __restrict__ cls_feat, const float* __restrict__ vocab_w,
    const float* __restrict__ vocab_b, const int* __restrict__ cnt,
    const int* __restrict__ idxList, float* __restrict__ out, int capB)
{
    const int count = min(*cnt, HW_);
    if (count <= capB) return;  // dense path handled it
    const int v0 = blockIdx.x * 64;

    __shared__ float sAT[16][64];
    __shared__ float sBT[16][64];
    __shared__ int   sIdx[64];

    const int tid = threadIdx.x;
    const int tx = tid & 15;
    const int ty = tid >> 4;
    const int r  = tid >> 2;
    const int kq = tid & 3;

    for (int jb = blockIdx.y; (jb << 6) < count; jb += gridDim.y) {
        const int j0 = jb << 6;
        __syncthreads();
        if (tid < 64) {
            int j = j0 + tid;
            sIdx[tid] = (j < count) ? idxList[j] : -1;
        }
        __syncthreads();
        const int hwj = sIdx[r];

        float acc[4][4] = {};
        for (int k0 = 0; k0 < C_; k0 += 16) {
            float4 a4 = make_float4(0.f, 0.f, 0.f, 0.f);
            if (v0 + r < NC_)
                a4 = *(const float4*)(vocab_w + (size_t)(v0 + r) * C_ + k0 + kq * 4);
            float b0 = 0.f, b1 = 0.f, b2 = 0.f, b3 = 0.f;
            if (hwj >= 0) {
                const float* bp = cls_feat + (size_t)(k0 + kq * 4) * HW_ + hwj;
                b0 = bp[0]; b1 = bp[HW_]; b2 = bp[2 * HW_]; b3 = bp[3 * HW_];
            }
            __syncthreads();
            sAT[kq * 4 + 0][r] = a4.x; sAT[kq * 4 + 1][r] = a4.y;
            sAT[kq * 4 + 2][r] = a4.z; sAT[kq * 4 + 3][r] = a4.w;
            sBT[kq * 4 + 0][r] = b0;   sBT[kq * 4 + 1][r] = b1;
            sBT[kq * 4 + 2][r] = b2;   sBT[kq * 4 + 3][r] = b3;
            __syncthreads();
            #pragma unroll
            for (int kk = 0; kk < 16; ++kk) {
                const float4 av = *(const float4*)&sAT[kk][ty * 4];
                const float4 bv = *(const float4*)&sBT[kk][tx * 4];
                acc[0][0] += av.x * bv.x; acc[0][1] += av.x * bv.y;
                acc[0][2] += av.x * bv.z; acc[0][3] += av.x * bv.w;
                acc[1][0] += av.y * bv.x; acc[1][1] += av.y * bv.y;
                acc[1][2] += av.y * bv.z; acc[1][3] += av.y * bv.w;
                acc[2][0] += av.z * bv.x; acc[2][1] += av.z * bv.y;
                acc[2][2] += av.z * bv.z; acc[2][3] += av.z * bv.w;
                acc[3][0] += av.w * bv.x; acc[3][1] += av.w * bv.y;
                acc[3][2] += av.w * bv.z; acc[3][3] += av.w * bv.w;
            }
        }
        #pragma unroll
        for (int a = 0; a < 4; ++a) {
            int v = v0 + ty * 4 + a;
            if (v >= NC_) continue;
            float bias = vocab_b[v];
            #pragma unroll
            for (int b = 0; b < 4; ++b) {
                int j = j0 + tx * 4 + b;
                if (j < count) {
                    int hw = sIdx[tx * 4 + b];
                    out[CLS_OFF_ + (size_t)v * HW_ + hw] = acc[a][b] + bias;
                }
            }
        }
    }
}

// ----------------------------------------------------------------- launch
extern "C" void kernel_launch(void* const* d_in, const int* in_sizes, int n_in,
                              void* d_out, int out_size, void* d_ws,
                              size_t ws_size, hipStream_t stream) {
    const float* cls_feat = (const float*)d_in[0];
    const float* loc_feat = (const float*)d_in[1];
    const float* conf     = (const float*)d_in[2];
    const float* pf_w     = (const float*)d_in[3];
    const float* pf_b     = (const float*)d_in[4];
    const float* vocab_w  = (const float*)d_in[5];
    const float* vocab_b  = (const float*)d_in[6];
    const float* loc_w    = (const float*)d_in[7];
    const float* loc_b    = (const float*)d_in[8];
    float* out = (float*)d_out;

    int*   cnt      = (int*)d_ws;
    int*   idxList  = (int*)((char*)d_ws + 4096);
    int*   jLut     = (int*)((char*)d_ws + 4096 + (size_t)HW_ * 4);
    size_t fixed    = 4096 + (size_t)HW_ * 4 * 2;
    size_t atBytes  = (size_t)(C_ / 4) * VPAD_ * 4 * sizeof(float);  // 2.49 MB
    size_t bdtBytes = (size_t)1024 * C_ * sizeof(float);             // 2.00 MB
    size_t tmpBytes = (size_t)1024 * VPAD_ * sizeof(float);          // 4.98 MB
    float* AT4      = (float*)((char*)d_ws + fixed);
    float* BdT      = (float*)((char*)d_ws + fixed + atBytes);
    float* clsTmp   = (float*)((char*)d_ws + fixed + atBytes + bdtBytes);

    int jcap = 0;
    if (ws_size >= fixed + atBytes + bdtBytes + tmpBytes) jcap = 1024;

    hipLaunchKernelGGL(k_init, dim3(1), dim3(1), 0, stream, cnt);
    hipLaunchKernelGGL(k_pre, dim3(PF_BLOCKS_ + TRANS_BLOCKS_), dim3(256),
                       0, stream,
                       cls_feat, conf, pf_w, pf_b, vocab_w, out, cnt,
                       idxList, jLut, AT4, jcap);
    if (jcap > 0) {
        hipLaunchKernelGGL(k_gatherJ, dim3(512), dim3(256), 0, stream,
                           cls_feat, cnt, idxList, BdT, jcap);
        hipLaunchKernelGGL(k_gemm6t, dim3(19, 1024 / 4), dim3(256), 0, stream,
                           AT4, vocab_b, cnt, BdT, clsTmp, jcap);
    }
    hipLaunchKernelGGL(k_mega, dim3(LOC_BLOCKS_ + FILL_BLOCKS_), dim3(256),
                       0, stream,
                       loc_feat, vocab_b, loc_w, loc_b, cnt, jLut, clsTmp,
                       out, jcap);
    hipLaunchKernelGGL(k_gemm_fallback, dim3((NC_ + 63) / 64, 8), dim3(256),
                       0, stream, cls_feat, vocab_w, vocab_b, cnt, idxList,
                       out, jcap);
}

// Round 17
// 62.072 us; speedup vs baseline: 1.1314x; 1.1314x over previous
//
#include <hip/hip_runtime.h>
#include <math.h>

// LRPCHead: C=512, H=W=160 (HW=25600), NC=1203, LC=64
// Outputs (flat, fp32): loc_out [64*25600] | cls_out [1203*25600] | mask [25600]

constexpr int C_    = 512;
constexpr int HW_   = 25600;
constexpr int NC_   = 1203;
constexpr int VPAD_ = 1216;   // padded v-extent for AT (19*64)

constexpr int LOC_OFF_  = 0;
constexpr int CLS_OFF_  = 64 * HW_;              // 1,638,400
constexpr int MASK_OFF_ = CLS_OFF_ + NC_ * HW_;  // 32,435,200

constexpr int PF_BLOCKS_    = HW_ / 64;  // 400
constexpr int LOC_BLOCKS_   = 400;       // 100 hw-tiles x 4 channel-tiles
constexpr int FILL_BLOCKS_  = 2048;
constexpr int TRANS_BLOCKS_ = 19 * 8;    // 152: v-tiles x k-tiles of 64

typedef float vfloat4 __attribute__((ext_vector_type(4)));

// ---------------------------------------------------------------- init
__global__ void k_init(int* cnt) { *cnt = 0; }

// ---- fused: pf mask+compact | loc conv | cls bias fill | vocab transpose
// (verbatim round-12 body — proven, 62.9 µs state)
__global__ __launch_bounds__(256) void k_main(
    const float* __restrict__ cls_feat, const float* __restrict__ loc_feat,
    const float* __restrict__ conf, const float* __restrict__ pf_w,
    const float* __restrict__ pf_b, const float* __restrict__ vocab_w,
    const float* __restrict__ vocab_b, const float* __restrict__ loc_w,
    const float* __restrict__ loc_b, float* __restrict__ out,
    int* __restrict__ cnt, int* __restrict__ idxList,
    float* __restrict__ AT4, int jcap)
{
    const int bid = blockIdx.x;
    const int tid = threadIdx.x;

    if (bid < PF_BLOCKS_) {
        __shared__ double sPart[256];
        const int hwi   = tid & 63;
        const int slice = tid >> 6;
        const int hw    = bid * 64 + hwi;
        const float* p  = cls_feat + (size_t)slice * 128 * HW_ + hw;
        const float* w  = pf_w + slice * 128;
        double acc = 0.0;
        #pragma unroll 4
        for (int k = 0; k < 128; ++k)
            acc += (double)w[k] * (double)p[(size_t)k * HW_];
        sPart[tid] = acc;
        __syncthreads();
        if (slice == 0) {
            double s = sPart[hwi] + sPart[64 + hwi] + sPart[128 + hwi] +
                       sPart[192 + hwi] + (double)pf_b[0];
            double sig = 1.0 / (1.0 + exp(-s));
            bool m = sig > (double)conf[0];
            out[MASK_OFF_ + hw] = m ? 1.0f : 0.0f;
            if (m) {
                int pos = atomicAdd(cnt, 1);
                if (pos < HW_) idxList[pos] = hw;
            }
        }
    } else if (bid < PF_BLOCKS_ + LOC_BLOCKS_) {
        const int j   = bid - PF_BLOCKS_;
        const int hwb = j % 100;
        const int o0  = (j / 100) * 16;
        __shared__ float sw[16][64];
        for (int i = tid; i < 16 * 64; i += 256)
            sw[i >> 6][i & 63] = loc_w[(o0 + (i >> 6)) * 64 + (i & 63)];
        __syncthreads();
        const int hw = hwb * 256 + tid;
        float acc[16];
        #pragma unroll
        for (int r = 0; r < 16; ++r) acc[r] = loc_b[o0 + r];
        for (int i = 0; i < 64; ++i) {
            float f = loc_feat[(size_t)i * HW_ + hw];
            #pragma unroll
            for (int r = 0; r < 16; ++r) acc[r] += sw[r][i] * f;
        }
        #pragma unroll
        for (int r = 0; r < 16; ++r)
            out[LOC_OFF_ + (size_t)(o0 + r) * HW_ + hw] = acc[r];
    } else if (bid < PF_BLOCKS_ + LOC_BLOCKS_ + FILL_BLOCKS_) {
        const int fb = bid - PF_BLOCKS_ - LOC_BLOCKS_;
        const int total4 = NC_ * HW_ / 4;  // 7,699,200 float4s
        vfloat4* o = (vfloat4*)(out + CLS_OFF_);
        for (int i = fb * 256 + tid; i < total4; i += FILL_BLOCKS_ * 256) {
            int v = i / (HW_ / 4);
            float b = vocab_b[v];
            vfloat4 val = {b, b, b, b};
            __builtin_nontemporal_store(val, &o[i]);
        }
    } else {
        // transpose vocab_w -> AT4[(k/4)][v][4]
        if (jcap <= 0) return;
        const int tb = bid - PF_BLOCKS_ - LOC_BLOCKS_ - FILL_BLOCKS_;
        const int v0 = (tb % 19) * 64;
        const int k0 = (tb / 19) * 64;
        __shared__ float t[64][65];
        const int c  = tid & 63;
        const int r4 = tid >> 6;
        #pragma unroll
        for (int i = 0; i < 16; ++i) {
            const int r = r4 * 16 + i;
            const int v = v0 + r;
            t[r][c] = (v < NC_) ? vocab_w[(size_t)v * C_ + k0 + c] : 0.f;
        }
        __syncthreads();
        #pragma unroll
        for (int i = 0; i < 16; ++i) {
            const int k  = r4 * 16 + i;
            const int kg = k0 + k;
            AT4[((size_t)(kg >> 2) * VPAD_ + v0 + c) * 4 + (kg & 3)] = t[c][k];
        }
    }
}

// ------------- gather live columns j-major: BdT[j][k] (proven)
__global__ __launch_bounds__(256) void k_gatherJ(
    const float* __restrict__ cls_feat, const int* __restrict__ cnt,
    const int* __restrict__ idxList, float* __restrict__ BdT, int jcap)
{
    const int count = min(*cnt, HW_);
    if (count > jcap) return;  // fallback path will handle
    const int t = threadIdx.x;
    for (int j = blockIdx.x; j < count; j += gridDim.x) {
        const int hw = idxList[j];
        BdT[(size_t)j * C_ + t]       = cls_feat[(size_t)t * HW_ + hw];
        BdT[(size_t)j * C_ + 256 + t] = cls_feat[(size_t)(256 + t) * HW_ + hw];
    }
}

// ------------- dense GEMM, XCD-pinned: all j-quads of a v-tile land on the
// SAME XCD (id%8 round-robin) so AT4's 128KB/v-tile is HBM-fetched once per
// XCD and re-read from local L2. Body = round-12 gemm6 (proven).
// grid (8, 768): x = xcd, slot = y; vt = x + 8*(slot%3); jq = slot/3.
__global__ __launch_bounds__(256) void k_gemm6x(
    const float* __restrict__ AT4, const float* __restrict__ vocab_b,
    const int* __restrict__ cnt, const int* __restrict__ idxList,
    const float* __restrict__ BdT, float* __restrict__ out, int jcap)
{
    const int count = min(*cnt, HW_);
    if (count == 0 || count > jcap) return;

    const int slot = blockIdx.y;
    const int vt   = blockIdx.x + 8 * (slot % 3);   // 0..23
    if (vt >= 19) return;
    const int jBase = (slot / 3) * 4;               // j-quad * 4
    if (jBase >= count) return;

    const int tid  = threadIdx.x;
    const int lane = tid & 63;
    const int w    = __builtin_amdgcn_readfirstlane(tid >> 6);  // wave 0..3
    const int v0   = vt * 64;
    const int v    = v0 + lane;
    const float* __restrict__ Acol = AT4 + (size_t)v * 4;

    const int j0 = jBase + 0, j1 = jBase + 1, j2 = jBase + 2, j3 = jBase + 3;
    const float* __restrict__ B0 = BdT + (size_t)(j0 < count ? j0 : 0) * C_;
    const float* __restrict__ B1 = BdT + (size_t)(j1 < count ? j1 : 0) * C_;
    const float* __restrict__ B2 = BdT + (size_t)(j2 < count ? j2 : 0) * C_;
    const float* __restrict__ B3 = BdT + (size_t)(j3 < count ? j3 : 0) * C_;

    vfloat4 ac0 = {0,0,0,0}, ac1 = {0,0,0,0}, ac2 = {0,0,0,0}, ac3 = {0,0,0,0};
    const int kqBeg = w * 32;          // this wave's 128-k slice
    #pragma unroll 8
    for (int q = 0; q < 32; ++q) {
        const int kq = kqBeg + q;
        const vfloat4 a  = *(const vfloat4*)(Acol + (size_t)kq * VPAD_ * 4);
        const vfloat4 b0 = *(const vfloat4*)(B0 + kq * 4);
        const vfloat4 b1 = *(const vfloat4*)(B1 + kq * 4);
        const vfloat4 b2 = *(const vfloat4*)(B2 + kq * 4);
        const vfloat4 b3 = *(const vfloat4*)(B3 + kq * 4);
        ac0 += a * b0; ac1 += a * b1; ac2 += a * b2; ac3 += a * b3;
    }

    __shared__ float sRed[4][4][64];
    sRed[w][0][lane] = (ac0.x + ac0.y) + (ac0.z + ac0.w);
    sRed[w][1][lane] = (ac1.x + ac1.y) + (ac1.z + ac1.w);
    sRed[w][2][lane] = (ac2.x + ac2.y) + (ac2.z + ac2.w);
    sRed[w][3][lane] = (ac3.x + ac3.y) + (ac3.z + ac3.w);
    __syncthreads();

    if (tid < 64 && v < NC_) {
        const float bias = vocab_b[v];
        #pragma unroll
        for (int jj = 0; jj < 4; ++jj) {
            const int j = jBase + jj;
            if (j < count) {
                const float s =
                    (sRed[0][jj][lane] + sRed[1][jj][lane]) +
                    (sRed[2][jj][lane] + sRed[3][jj][lane]);
                const int hw = idxList[j];
                out[CLS_OFF_ + (size_t)v * HW_ + hw] = s + bias;
            }
        }
    }
}

// --------------------------- fallback: direct scatter-gather GEMM (count>jcap)
__global__ __launch_bounds__(256) void k_gemm_fallback(
    const float* __restrict__ cls_feat, const float* __restrict__ vocab_w,
    const float* __restrict__ vocab_b, const int* __restrict__ cnt,
    const int* __restrict__ idxList, float* __restrict__ out, int capB)
{
    const int count = min(*cnt, HW_);
    if (count <= capB) return;  // dense path handled it
    const int v0 = blockIdx.x * 64;

    __shared__ float sAT[16][64];
    __shared__ float sBT[16][64];
    __shared__ int   sIdx[64];

    const int tid = threadIdx.x;
    const int tx = tid & 15;
    const int ty = tid >> 4;
    const int r  = tid >> 2;
    const int kq = tid & 3;

    for (int jb = blockIdx.y; (jb << 6) < count; jb += gridDim.y) {
        const int j0 = jb << 6;
        __syncthreads();
        if (tid < 64) {
            int j = j0 + tid;
            sIdx[tid] = (j < count) ? idxList[j] : -1;
        }
        __syncthreads();
        const int hwj = sIdx[r];

        float acc[4][4] = {};
        for (int k0 = 0; k0 < C_; k0 += 16) {
            float4 a4 = make_float4(0.f, 0.f, 0.f, 0.f);
            if (v0 + r < NC_)
                a4 = *(const float4*)(vocab_w + (size_t)(v0 + r) * C_ + k0 + kq * 4);
            float b0 = 0.f, b1 = 0.f, b2 = 0.f, b3 = 0.f;
            if (hwj >= 0) {
                const float* bp = cls_feat + (size_t)(k0 + kq * 4) * HW_ + hwj;
                b0 = bp[0]; b1 = bp[HW_]; b2 = bp[2 * HW_]; b3 = bp[3 * HW_];
            }
            __syncthreads();
            sAT[kq * 4 + 0][r] = a4.x; sAT[kq * 4 + 1][r] = a4.y;
            sAT[kq * 4 + 2][r] = a4.z; sAT[kq * 4 + 3][r] = a4.w;
            sBT[kq * 4 + 0][r] = b0;   sBT[kq * 4 + 1][r] = b1;
            sBT[kq * 4 + 2][r] = b2;   sBT[kq * 4 + 3][r] = b3;
            __syncthreads();
            #pragma unroll
            for (int kk = 0; kk < 16; ++kk) {
                const float4 av = *(const float4*)&sAT[kk][ty * 4];
                const float4 bv = *(const float4*)&sBT[kk][tx * 4];
                acc[0][0] += av.x * bv.x; acc[0][1] += av.x * bv.y;
                acc[0][2] += av.x * bv.z; acc[0][3] += av.x * bv.w;
                acc[1][0] += av.y * bv.x; acc[1][1] += av.y * bv.y;
                acc[1][2] += av.y * bv.z; acc[1][3] += av.y * bv.w;
                acc[2][0] += av.z * bv.x; acc[2][1] += av.z * bv.y;
                acc[2][2] += av.z * bv.z; acc[2][3] += av.z * bv.w;
                acc[3][0] += av.w * bv.x; acc[3][1] += av.w * bv.y;
                acc[3][2] += av.w * bv.z; acc[3][3] += av.w * bv.w;
            }
        }
        #pragma unroll
        for (int a = 0; a < 4; ++a) {
            int v = v0 + ty * 4 + a;
            if (v >= NC_) continue;
            float bias = vocab_b[v];
            #pragma unroll
            for (int b = 0; b < 4; ++b) {
                int j = j0 + tx * 4 + b;
                if (j < count) {
                    int hw = sIdx[tx * 4 + b];
                    out[CLS_OFF_ + (size_t)v * HW_ + hw] = acc[a][b] + bias;
                }
            }
        }
    }
}

// ----------------------------------------------------------------- launch
extern "C" void kernel_launch(void* const* d_in, const int* in_sizes, int n_in,
                              void* d_out, int out_size, void* d_ws,
                              size_t ws_size, hipStream_t stream) {
    const float* cls_feat = (const float*)d_in[0];
    const float* loc_feat = (const float*)d_in[1];
    const float* conf     = (const float*)d_in[2];
    const float* pf_w     = (const float*)d_in[3];
    const float* pf_b     = (const float*)d_in[4];
    const float* vocab_w  = (const float*)d_in[5];
    const float* vocab_b  = (const float*)d_in[6];
    const float* loc_w    = (const float*)d_in[7];
    const float* loc_b    = (const float*)d_in[8];
    float* out = (float*)d_out;

    int*   cnt     = (int*)d_ws;
    int*   idxList = (int*)((char*)d_ws + 4096);
    size_t fixed   = 4096 + (size_t)HW_ * sizeof(int);
    size_t atBytes = (size_t)(C_ / 4) * VPAD_ * 4 * sizeof(float);  // 2.49 MB
    float* AT4     = (float*)((char*)d_ws + fixed);
    float* BdT     = (float*)((char*)d_ws + fixed + atBytes);

    int jcap = 0;
    if (ws_size > fixed + atBytes) {
        size_t cols = (ws_size - fixed - atBytes) / ((size_t)C_ * sizeof(float));
        jcap = (int)(cols > 1024 ? 1024 : cols);
        jcap &= ~63;
    }

    hipLaunchKernelGGL(k_init, dim3(1), dim3(1), 0, stream, cnt);
    hipLaunchKernelGGL(k_main,
                       dim3(PF_BLOCKS_ + LOC_BLOCKS_ + FILL_BLOCKS_ +
                            TRANS_BLOCKS_),
                       dim3(256), 0, stream,
                       cls_feat, loc_feat, conf, pf_w, pf_b, vocab_w, vocab_b,
                       loc_w, loc_b, out, cnt, idxList, AT4, jcap);
    if (jcap > 0) {
        hipLaunchKernelGGL(k_gatherJ, dim3(512), dim3(256), 0, stream,
                           cls_feat, cnt, idxList, BdT, jcap);
        hipLaunchKernelGGL(k_gemm6x, dim3(8, 768), dim3(256), 0, stream,
                           AT4, vocab_b, cnt, idxList, BdT, out, jcap);
    }
    hipLaunchKernelGGL(k_gemm_fallback, dim3((NC_ + 63) / 64, 8), dim3(256),
                       0, stream, cls_feat, vocab_w, vocab_b, cnt, idxList,
                       out, jcap);
}